// Round 2
// baseline (7726.646 us; speedup 1.0000x reference)
//
#include <hip/hip_runtime.h>

#define ALPHA 0.2f

__device__ __forceinline__ float lrelu_f(float x){ return x > 0.f ? x : ALPHA * x; }

// ---------------- Encoder: 3x3 stride-2 SAME conv (pad lo=0, hi=1) ----------------
template<int H,int W,int CIN,int COUT,bool LRELU>
__global__ __launch_bounds__(256) void conv3x3_s2_k(const float* __restrict__ in,
    const float* __restrict__ w, const float* __restrict__ bias, float* __restrict__ out,
    int total){
  constexpr int Ho = H/2, Wo = W/2;
  int t = blockIdx.x * 256 + threadIdx.x;
  if (t >= total) return;
  int o = t % COUT;
  int p = t / COUT;
  int x = p % Wo; p /= Wo;
  int y = p % Ho; int n = p / Ho;
  float acc = bias[o];
  #pragma unroll
  for (int ky=0; ky<3; ky++){
    int iy = 2*y + ky;
    if (iy >= H) continue;
    #pragma unroll
    for (int kx=0; kx<3; kx++){
      int ix = 2*x + kx;
      if (ix >= W) continue;
      const float* ip = in + (((size_t)n*H + iy)*W + ix)*CIN;
      const float* wp = w + ((ky*3+kx)*CIN)*COUT + o;
      if constexpr (CIN == 3){
        acc += ip[0]*wp[0];
        acc += ip[1]*wp[COUT];
        acc += ip[2]*wp[2*COUT];
      } else {
        #pragma unroll
        for (int c=0; c<CIN; c+=4){
          float4 v = *(const float4*)(ip + c);
          acc += v.x * wp[(c+0)*COUT];
          acc += v.y * wp[(c+1)*COUT];
          acc += v.z * wp[(c+2)*COUT];
          acc += v.w * wp[(c+3)*COUT];
        }
      }
    }
  }
  if constexpr (LRELU) acc = lrelu_f(acc);
  out[t] = acc;
}

// ---------------- Fused enc4 (1x1 conv 64->32) + vector-quantize ----------------
template<int CIN,int D,int K>
__global__ __launch_bounds__(256) void enc4_vq_k(const float* __restrict__ in,
    const float* __restrict__ w, const float* __restrict__ bias,
    const float* __restrict__ cb, float* __restrict__ q, int npix){
  int i = blockIdx.x*256 + threadIdx.x;
  if (i >= npix) return;
  const float* ip = in + (size_t)i*CIN;
  float z[D];
  #pragma unroll
  for (int d=0; d<D; d++) z[d] = bias[d];
  for (int c=0; c<CIN; c+=4){
    float4 v = *(const float4*)(ip + c);
    #pragma unroll
    for (int d=0; d<D; d++){
      z[d] += v.x * w[(c+0)*D + d];
      z[d] += v.y * w[(c+1)*D + d];
      z[d] += v.z * w[(c+2)*D + d];
      z[d] += v.w * w[(c+3)*D + d];
    }
  }
  float z2 = 0.f;
  #pragma unroll
  for (int d=0; d<D; d++) z2 += z[d]*z[d];
  float best = 3.4e38f; int bi = 0;
  for (int k=0; k<K; k++){
    float e2 = 0.f, dot = 0.f;
    #pragma unroll
    for (int d=0; d<D; d++){
      float cv = cb[d*K + k];
      e2  += cv*cv;
      dot += z[d]*cv;
    }
    float dist = z2 + e2 - 2.f*dot;
    if (dist < best){ best = dist; bi = k; }   // strict < == first-min (jnp.argmin)
  }
  float* qp = q + (size_t)i*D;
  #pragma unroll
  for (int d=0; d<D; d++) qp[d] = cb[d*K + bi];
}

// ---------------- Decoder: conv_transpose 3x3 stride-2 SAME (JAX, unflipped kernel) ----
// out[y]: uy = y+ky-2 must be even; iy = uy/2 in [0,H)
template<int H,int W,int CIN,int COUT,bool LRELU>
__global__ __launch_bounds__(256) void deconv3x3_s2_k(const float* __restrict__ in,
    const float* __restrict__ w, const float* __restrict__ bias, float* __restrict__ out,
    int total){
  constexpr int Ho = 2*H, Wo = 2*W;
  int t = blockIdx.x*256 + threadIdx.x;
  if (t >= total) return;
  int o = t % COUT;
  int p = t / COUT;
  int x = p % Wo; p /= Wo;
  int y = p % Ho; int n = p / Ho;
  float acc = bias[o];
  #pragma unroll
  for (int ky=0; ky<3; ky++){
    int uy = y + ky - 2;
    if (uy & 1) continue;
    int iy = uy >> 1;
    if (iy < 0 || iy >= H) continue;
    #pragma unroll
    for (int kx=0; kx<3; kx++){
      int ux = x + kx - 2;
      if (ux & 1) continue;
      int ix = ux >> 1;
      if (ix < 0 || ix >= W) continue;
      const float* ip = in + (((size_t)n*H + iy)*W + ix)*CIN;
      const float* wp = w + ((ky*3+kx)*CIN)*COUT + o;
      #pragma unroll
      for (int c=0; c<CIN; c+=4){
        float4 v = *(const float4*)(ip + c);
        acc += v.x * wp[(c+0)*COUT];
        acc += v.y * wp[(c+1)*COUT];
        acc += v.z * wp[(c+2)*COUT];
        acc += v.w * wp[(c+3)*COUT];
      }
    }
  }
  if constexpr (LRELU) acc = lrelu_f(acc);
  out[t] = acc;
}

// ---------------- dec4: conv_transpose s1 == plain 3x3 pad-1 conv, Cout=1 ----------------
template<int H,int W,int CIN>
__global__ __launch_bounds__(256) void conv3x3_s1_co1_k(const float* __restrict__ in,
    const float* __restrict__ w, const float* __restrict__ bias, float* __restrict__ out,
    int total){
  int t = blockIdx.x*256 + threadIdx.x;
  if (t >= total) return;
  int x = t % W;
  int p = t / W;
  int y = p % H; int n = p / H;
  float acc = bias[0];
  #pragma unroll
  for (int ky=0; ky<3; ky++){
    int iy = y + ky - 1;
    if (iy < 0 || iy >= H) continue;
    #pragma unroll
    for (int kx=0; kx<3; kx++){
      int ix = x + kx - 1;
      if (ix < 0 || ix >= W) continue;
      const float* ip = in + (((size_t)n*H + iy)*W + ix)*CIN;
      const float* wp = w + (ky*3+kx)*CIN;   // Cout==1 -> contiguous over c
      #pragma unroll
      for (int c=0; c<CIN; c+=4){
        float4 v  = *(const float4*)(ip + c);
        float4 wv = *(const float4*)(wp + c);
        acc += v.x*wv.x;
        acc += v.y*wv.y;
        acc += v.z*wv.z;
        acc += v.w*wv.w;
      }
    }
  }
  out[t] = acc;
}

extern "C" void kernel_launch(void* const* d_in, const int* in_sizes, int n_in,
                              void* d_out, int out_size, void* d_ws, size_t ws_size,
                              hipStream_t stream) {
  const float* x   = (const float*)d_in[0];
  const float* e1w = (const float*)d_in[1];  const float* e1b = (const float*)d_in[2];
  const float* e2w = (const float*)d_in[3];  const float* e2b = (const float*)d_in[4];
  const float* e3w = (const float*)d_in[5];  const float* e3b = (const float*)d_in[6];
  const float* e4w = (const float*)d_in[7];  const float* e4b = (const float*)d_in[8];
  const float* cb  = (const float*)d_in[9];
  const float* d1w = (const float*)d_in[10]; const float* d1b = (const float*)d_in[11];
  const float* d2w = (const float*)d_in[12]; const float* d2b = (const float*)d_in[13];
  const float* d3w = (const float*)d_in[14]; const float* d3b = (const float*)d_in[15];
  const float* d4w = (const float*)d_in[16]; const float* d4b = (const float*)d_in[17];
  float* out = (float*)d_out;

  // Per-image ping-pong footprint:
  //   ping A = max(h1=2MiB, h3=0.25, d1=1, d3=8) = 8 MiB/img
  //   pong B = max(h2=1MiB, q=0.125, d2=4)       = 4 MiB/img
  // Pick largest batch chunk Bc (power of two dividing 32) fitting ws_size.
  const size_t MiB = 1ull << 20;
  int Bc = 32;
  while (Bc > 1 && (size_t)Bc * 12 * MiB > ws_size) Bc >>= 1;

  char* wsb = (char*)d_ws;
  float* A  = (float*)wsb;                              // Bc * 8 MiB
  float* Bf = (float*)(wsb + (size_t)Bc * 8 * MiB);     // Bc * 4 MiB

  for (int n0 = 0; n0 < 32; n0 += Bc) {
    const float* xc = x   + (size_t)n0 * 256*256*3;
    float*      oc  = out + (size_t)n0 * 256*256;

    int t1 = Bc*128*128*32;   // enc1 out
    conv3x3_s2_k<256,256,3,32,true><<<t1/256, 256, 0, stream>>>(xc, e1w, e1b, A, t1);
    int t2 = Bc*64*64*64;     // enc2 out
    conv3x3_s2_k<128,128,32,64,true><<<t2/256, 256, 0, stream>>>(A, e2w, e2b, Bf, t2);
    int t3 = Bc*32*32*64;     // enc3 out
    conv3x3_s2_k<64,64,64,64,true><<<t3/256, 256, 0, stream>>>(Bf, e3w, e3b, A, t3);
    int npix = Bc*32*32;      // enc4+VQ out: [Bc,32,32,32]
    enc4_vq_k<64,32,64><<<npix/256, 256, 0, stream>>>(A, e4w, e4b, cb, Bf, npix);
    int t5 = Bc*64*64*64;     // dec1 out
    deconv3x3_s2_k<32,32,32,64,true><<<t5/256, 256, 0, stream>>>(Bf, d1w, d1b, A, t5);
    int t6 = Bc*128*128*64;   // dec2 out
    deconv3x3_s2_k<64,64,64,64,true><<<t6/256, 256, 0, stream>>>(A, d2w, d2b, Bf, t6);
    int t7 = Bc*256*256*32;   // dec3 out
    deconv3x3_s2_k<128,128,64,32,true><<<t7/256, 256, 0, stream>>>(Bf, d3w, d3b, A, t7);
    int t8 = Bc*256*256;      // dec4 out
    conv3x3_s1_co1_k<256,256,32><<<t8/256, 256, 0, stream>>>(A, d4w, d4b, oc, t8);
  }
}

// Round 3
// 2806.762 us; speedup vs baseline: 2.7529x; 2.7529x over previous
//
#include <hip/hip_runtime.h>

#define ALPHA 0.2f

__device__ __forceinline__ float lrelu_f(float x){ return x > 0.f ? x : ALPHA * x; }

// ============ Encoder: 3x3 stride-2 SAME conv (pad lo=0,hi=1), TO outputs/thread ============
template<int H,int W,int CIN,int COUT,int TO,bool LRELU>
__global__ __launch_bounds__(256) void conv3x3_s2_to_k(const float* __restrict__ in,
    const float* __restrict__ w, const float* __restrict__ bias, float* __restrict__ out,
    int total){
  constexpr int Ho = H/2, Wo = W/2, OB = COUT/TO;
  int t = blockIdx.x * 256 + threadIdx.x;
  if (t >= total) return;
  int ob = t % OB;
  int p  = t / OB;
  int x  = p % Wo; p /= Wo;
  int y  = p % Ho; int n = p / Ho;

  float acc[TO];
  #pragma unroll
  for (int j4 = 0; j4 < TO/4; j4++){
    float4 bv = *(const float4*)(bias + ob*TO + j4*4);
    acc[j4*4+0]=bv.x; acc[j4*4+1]=bv.y; acc[j4*4+2]=bv.z; acc[j4*4+3]=bv.w;
  }

  #pragma unroll
  for (int ky=0; ky<3; ky++){
    int iy = 2*y + ky;
    if (iy >= H) continue;
    #pragma unroll
    for (int kx=0; kx<3; kx++){
      int ix = 2*x + kx;
      if (ix >= W) continue;
      const float* ip = in + (((size_t)n*H + iy)*W + ix)*CIN;
      const float* wp = w + ((ky*3+kx)*CIN)*COUT + ob*TO;
      if constexpr (CIN == 3){
        #pragma unroll
        for (int ci=0; ci<3; ci++){
          float v = ip[ci];
          #pragma unroll
          for (int j4=0; j4<TO/4; j4++){
            float4 wv = *(const float4*)(wp + ci*COUT + j4*4);
            acc[j4*4+0] += v*wv.x; acc[j4*4+1] += v*wv.y;
            acc[j4*4+2] += v*wv.z; acc[j4*4+3] += v*wv.w;
          }
        }
      } else {
        #pragma unroll 2
        for (int c=0; c<CIN; c+=4){
          float4 v = *(const float4*)(ip + c);
          #pragma unroll
          for (int ci=0; ci<4; ci++){
            float vc = (ci==0)?v.x:(ci==1)?v.y:(ci==2)?v.z:v.w;
            #pragma unroll
            for (int j4=0; j4<TO/4; j4++){
              float4 wv = *(const float4*)(wp + (c+ci)*COUT + j4*4);
              acc[j4*4+0] += vc*wv.x; acc[j4*4+1] += vc*wv.y;
              acc[j4*4+2] += vc*wv.z; acc[j4*4+3] += vc*wv.w;
            }
          }
        }
      }
    }
  }
  float* op = out + ((size_t)((n*Ho + y)*Wo + x))*COUT + ob*TO;
  #pragma unroll
  for (int j4=0; j4<TO/4; j4++){
    float4 r;
    r.x = LRELU ? lrelu_f(acc[j4*4+0]) : acc[j4*4+0];
    r.y = LRELU ? lrelu_f(acc[j4*4+1]) : acc[j4*4+1];
    r.z = LRELU ? lrelu_f(acc[j4*4+2]) : acc[j4*4+2];
    r.w = LRELU ? lrelu_f(acc[j4*4+3]) : acc[j4*4+3];
    *(float4*)(op + j4*4) = r;
  }
}

// ============ Fused enc4 (1x1 conv 64->32) + vector-quantize ============
template<int CIN,int D,int K>
__global__ __launch_bounds__(256) void enc4_vq_k(const float* __restrict__ in,
    const float* __restrict__ w, const float* __restrict__ bias,
    const float* __restrict__ cb, float* __restrict__ q, int npix){
  int i = blockIdx.x*256 + threadIdx.x;
  if (i >= npix) return;
  const float* ip = in + (size_t)i*CIN;
  float z[D];
  #pragma unroll
  for (int d=0; d<D; d++) z[d] = bias[d];
  for (int c=0; c<CIN; c+=4){
    float4 v = *(const float4*)(ip + c);
    #pragma unroll
    for (int d=0; d<D; d++){
      z[d] += v.x * w[(c+0)*D + d];
      z[d] += v.y * w[(c+1)*D + d];
      z[d] += v.z * w[(c+2)*D + d];
      z[d] += v.w * w[(c+3)*D + d];
    }
  }
  float z2 = 0.f;
  #pragma unroll
  for (int d=0; d<D; d++) z2 += z[d]*z[d];
  float best = 3.4e38f; int bi = 0;
  for (int k=0; k<K; k++){
    float e2 = 0.f, dot = 0.f;
    #pragma unroll
    for (int d=0; d<D; d++){
      float cv = cb[d*K + k];
      e2  += cv*cv;
      dot += z[d]*cv;
    }
    float dist = z2 + e2 - 2.f*dot;
    if (dist < best){ best = dist; bi = k; }   // strict < == first-min (jnp.argmin)
  }
  float* qp = q + (size_t)i*D;
  #pragma unroll
  for (int d=0; d<D; d++) qp[d] = cb[d*K + bi];
}

// ============ Decoder: conv_transpose 3x3 s2 SAME, parity-specialized, TO/thread ============
// Output pixel (y,x) = (2*yy+PY, 2*xx+PX). Valid taps: (PY+ky) even, (PX+kx) even.
// dy = (PY+ky-2)/2 in {-1,0}; iy = yy+dy (only lower-bound check needed).
template<int H,int W,int CIN,int COUT,int TO,int PY,int PX,bool LRELU>
__global__ __launch_bounds__(256) void deconv3x3_s2_p_k(const float* __restrict__ in,
    const float* __restrict__ w, const float* __restrict__ bias, float* __restrict__ out,
    int total){
  constexpr int Ho = 2*H, Wo = 2*W, OB = COUT/TO;
  int t = blockIdx.x*256 + threadIdx.x;
  if (t >= total) return;
  int ob = t % OB;
  int p  = t / OB;
  int xx = p % W; p /= W;
  int yy = p % H; int n = p / H;

  float acc[TO];
  #pragma unroll
  for (int j4 = 0; j4 < TO/4; j4++){
    float4 bv = *(const float4*)(bias + ob*TO + j4*4);
    acc[j4*4+0]=bv.x; acc[j4*4+1]=bv.y; acc[j4*4+2]=bv.z; acc[j4*4+3]=bv.w;
  }

  #pragma unroll
  for (int ky=0; ky<3; ky++){
    if ((PY + ky) & 1) continue;           // compile-time parity filter
    constexpr_int_marker:;
    const int dy = (PY + ky - 2) >> 1;     // -1 or 0 (exact for even numerator)
    int iy = yy + dy;
    if (dy < 0 && iy < 0) continue;
    #pragma unroll
    for (int kx=0; kx<3; kx++){
      if ((PX + kx) & 1) continue;
      const int dx = (PX + kx - 2) >> 1;
      int ix = xx + dx;
      if (dx < 0 && ix < 0) continue;
      const float* ip = in + (((size_t)n*H + iy)*W + ix)*CIN;
      const float* wp = w + ((ky*3+kx)*CIN)*COUT + ob*TO;
      #pragma unroll 2
      for (int c=0; c<CIN; c+=4){
        float4 v = *(const float4*)(ip + c);
        #pragma unroll
        for (int ci=0; ci<4; ci++){
          float vc = (ci==0)?v.x:(ci==1)?v.y:(ci==2)?v.z:v.w;
          #pragma unroll
          for (int j4=0; j4<TO/4; j4++){
            float4 wv = *(const float4*)(wp + (c+ci)*COUT + j4*4);
            acc[j4*4+0] += vc*wv.x; acc[j4*4+1] += vc*wv.y;
            acc[j4*4+2] += vc*wv.z; acc[j4*4+3] += vc*wv.w;
          }
        }
      }
    }
  }
  int y = 2*yy + PY, x = 2*xx + PX;
  float* op = out + ((size_t)((n*Ho + y)*Wo + x))*COUT + ob*TO;
  #pragma unroll
  for (int j4=0; j4<TO/4; j4++){
    float4 r;
    r.x = LRELU ? lrelu_f(acc[j4*4+0]) : acc[j4*4+0];
    r.y = LRELU ? lrelu_f(acc[j4*4+1]) : acc[j4*4+1];
    r.z = LRELU ? lrelu_f(acc[j4*4+2]) : acc[j4*4+2];
    r.w = LRELU ? lrelu_f(acc[j4*4+3]) : acc[j4*4+3];
    *(float4*)(op + j4*4) = r;
  }
}

// ============ dec4: conv_transpose s1 == plain 3x3 pad-1 conv, Cout=1 ============
template<int H,int W,int CIN>
__global__ __launch_bounds__(256) void conv3x3_s1_co1_k(const float* __restrict__ in,
    const float* __restrict__ w, const float* __restrict__ bias, float* __restrict__ out,
    int total){
  int t = blockIdx.x*256 + threadIdx.x;
  if (t >= total) return;
  int x = t % W;
  int p = t / W;
  int y = p % H; int n = p / H;
  float acc = bias[0];
  #pragma unroll
  for (int ky=0; ky<3; ky++){
    int iy = y + ky - 1;
    if (iy < 0 || iy >= H) continue;
    #pragma unroll
    for (int kx=0; kx<3; kx++){
      int ix = x + kx - 1;
      if (ix < 0 || ix >= W) continue;
      const float* ip = in + (((size_t)n*H + iy)*W + ix)*CIN;
      const float* wp = w + (ky*3+kx)*CIN;   // Cout==1 -> contiguous over c
      #pragma unroll
      for (int c=0; c<CIN; c+=4){
        float4 v  = *(const float4*)(ip + c);
        float4 wv = *(const float4*)(wp + c);
        acc += v.x*wv.x;
        acc += v.y*wv.y;
        acc += v.z*wv.z;
        acc += v.w*wv.w;
      }
    }
  }
  out[t] = acc;
}

// Helper to launch the 4 parity variants of a deconv layer.
#define LAUNCH_DECONV(H,W,CIN,COUT,TO,LR,inp,wp_,bp_,outp,nthreads)                          \
  do {                                                                                       \
    deconv3x3_s2_p_k<H,W,CIN,COUT,TO,0,0,LR><<<(nthreads)/256,256,0,stream>>>(inp,wp_,bp_,outp,nthreads); \
    deconv3x3_s2_p_k<H,W,CIN,COUT,TO,0,1,LR><<<(nthreads)/256,256,0,stream>>>(inp,wp_,bp_,outp,nthreads); \
    deconv3x3_s2_p_k<H,W,CIN,COUT,TO,1,0,LR><<<(nthreads)/256,256,0,stream>>>(inp,wp_,bp_,outp,nthreads); \
    deconv3x3_s2_p_k<H,W,CIN,COUT,TO,1,1,LR><<<(nthreads)/256,256,0,stream>>>(inp,wp_,bp_,outp,nthreads); \
  } while(0)

extern "C" void kernel_launch(void* const* d_in, const int* in_sizes, int n_in,
                              void* d_out, int out_size, void* d_ws, size_t ws_size,
                              hipStream_t stream) {
  const float* x   = (const float*)d_in[0];
  const float* e1w = (const float*)d_in[1];  const float* e1b = (const float*)d_in[2];
  const float* e2w = (const float*)d_in[3];  const float* e2b = (const float*)d_in[4];
  const float* e3w = (const float*)d_in[5];  const float* e3b = (const float*)d_in[6];
  const float* e4w = (const float*)d_in[7];  const float* e4b = (const float*)d_in[8];
  const float* cb  = (const float*)d_in[9];
  const float* d1w = (const float*)d_in[10]; const float* d1b = (const float*)d_in[11];
  const float* d2w = (const float*)d_in[12]; const float* d2b = (const float*)d_in[13];
  const float* d3w = (const float*)d_in[14]; const float* d3b = (const float*)d_in[15];
  const float* d4w = (const float*)d_in[16]; const float* d4b = (const float*)d_in[17];
  float* out = (float*)d_out;

  // Per-image ping-pong: A = max(h1,h3,d1,d3) = 8 MiB/img; B = max(h2,q,d2) = 4 MiB/img.
  const size_t MiB = 1ull << 20;
  int Bc = 32;
  while (Bc > 1 && (size_t)Bc * 12 * MiB > ws_size) Bc >>= 1;

  char* wsb = (char*)d_ws;
  float* A  = (float*)wsb;                              // Bc * 8 MiB
  float* Bf = (float*)(wsb + (size_t)Bc * 8 * MiB);     // Bc * 4 MiB

  for (int n0 = 0; n0 < 32; n0 += Bc) {
    const float* xc = x   + (size_t)n0 * 256*256*3;
    float*      oc  = out + (size_t)n0 * 256*256;

    // enc1: [Bc,256,256,3] -> [Bc,128,128,32], TO=8 -> OB=4
    int t1 = Bc*128*128*4;
    conv3x3_s2_to_k<256,256,3,32,8,true><<<t1/256,256,0,stream>>>(xc, e1w, e1b, A, t1);
    // enc2: -> [Bc,64,64,64], TO=8 -> OB=8
    int t2 = Bc*64*64*8;
    conv3x3_s2_to_k<128,128,32,64,8,true><<<t2/256,256,0,stream>>>(A, e2w, e2b, Bf, t2);
    // enc3: -> [Bc,32,32,64]
    int t3 = Bc*32*32*8;
    conv3x3_s2_to_k<64,64,64,64,8,true><<<t3/256,256,0,stream>>>(Bf, e3w, e3b, A, t3);
    // enc4 (1x1, 64->32) + VQ: -> q [Bc,32,32,32]
    int npix = Bc*32*32;
    enc4_vq_k<64,32,64><<<npix/256,256,0,stream>>>(A, e4w, e4b, cb, Bf, npix);
    // dec1: [Bc,32,32,32] -> [Bc,64,64,64]; per-parity threads = Bc*32*32*(64/8)
    int t5 = Bc*32*32*8;
    LAUNCH_DECONV(32,32,32,64,8,true, Bf, d1w, d1b, A, t5);
    // dec2: -> [Bc,128,128,64]; per-parity threads = Bc*64*64*8
    int t6 = Bc*64*64*8;
    LAUNCH_DECONV(64,64,64,64,8,true, A, d2w, d2b, Bf, t6);
    // dec3: -> [Bc,256,256,32]; per-parity threads = Bc*128*128*4
    int t7 = Bc*128*128*4;
    LAUNCH_DECONV(128,128,64,32,8,true, Bf, d3w, d3b, A, t7);
    // dec4: -> [Bc,256,256,1]
    int t8 = Bc*256*256;
    conv3x3_s1_co1_k<256,256,32><<<t8/256,256,0,stream>>>(A, d4w, d4b, oc, t8);
  }
}

// Round 4
// 1868.010 us; speedup vs baseline: 4.1363x; 1.5025x over previous
//
#include <hip/hip_runtime.h>

#define ALPHA 0.2f
__device__ __forceinline__ float lrelu_f(float x){ return x>0.f ? x : ALPHA*x; }
__device__ __forceinline__ float4 zero4(){ float4 z; z.x=z.y=z.z=z.w=0.f; return z; }

// ============ Encoder: 3x3 s2 SAME conv (pad lo=0,hi=1), TO chans x TX pixels per thread ====
template<int H,int W,int CIN,int COUT,int TO,int TX,bool LRELU>
__global__ __launch_bounds__(256) void conv3x3_s2_k(const float* __restrict__ in,
    const float* __restrict__ w, const float* __restrict__ bias, float* __restrict__ out,
    int total){
  constexpr int Ho=H/2, Wo=W/2, OB=COUT/TO, XB=Wo/TX;
  int t = blockIdx.x*256 + threadIdx.x;
  if (t >= total) return;
  int ob = t % OB; int p = t/OB;
  int xb = p % XB; p /= XB;
  int y  = p % Ho; int n = p/Ho;
  int x0 = xb*TX;

  float acc[TX][TO];
  #pragma unroll
  for (int j4=0;j4<TO/4;j4++){
    float4 bv = *(const float4*)(bias + ob*TO + j4*4);
    #pragma unroll
    for (int px=0;px<TX;px++){
      acc[px][j4*4+0]=bv.x; acc[px][j4*4+1]=bv.y;
      acc[px][j4*4+2]=bv.z; acc[px][j4*4+3]=bv.w;
    }
  }

  #pragma unroll
  for (int ky=0;ky<3;ky++){
    int iy = 2*y + ky;
    if (iy >= H) continue;
    const float* row = in + ((size_t)n*H + iy)*(size_t)(W*CIN);
    #pragma unroll
    for (int kx=0;kx<3;kx++){
      const float* wp = w + ((ky*3+kx)*CIN)*COUT + ob*TO;
      const float* ipx[TX]; bool okx[TX];
      #pragma unroll
      for (int px=0;px<TX;px++){
        int ix = 2*(x0+px)+kx;
        okx[px] = (ix < W);
        ipx[px] = row + (size_t)(okx[px] ? ix : (W-1))*CIN;
      }
      if constexpr (CIN==3){
        #pragma unroll
        for (int ci=0;ci<3;ci++){
          float4 wv[TO/4];
          #pragma unroll
          for (int j4=0;j4<TO/4;j4++) wv[j4] = *(const float4*)(wp + ci*COUT + j4*4);
          #pragma unroll
          for (int px=0;px<TX;px++){
            float v = okx[px] ? ipx[px][ci] : 0.f;
            #pragma unroll
            for (int j4=0;j4<TO/4;j4++){
              acc[px][j4*4+0] += v*wv[j4].x; acc[px][j4*4+1] += v*wv[j4].y;
              acc[px][j4*4+2] += v*wv[j4].z; acc[px][j4*4+3] += v*wv[j4].w;
            }
          }
        }
      } else {
        for (int c=0;c<CIN;c+=4){
          float4 wv[4][TO/4];
          #pragma unroll
          for (int ci=0;ci<4;ci++)
            #pragma unroll
            for (int j4=0;j4<TO/4;j4++)
              wv[ci][j4] = *(const float4*)(wp + (c+ci)*COUT + j4*4);
          #pragma unroll
          for (int px=0;px<TX;px++){
            float4 vv = *(const float4*)(ipx[px]+c);
            if (!okx[px]) vv = zero4();
            float vc[4] = {vv.x, vv.y, vv.z, vv.w};
            #pragma unroll
            for (int ci=0;ci<4;ci++)
              #pragma unroll
              for (int j4=0;j4<TO/4;j4++){
                acc[px][j4*4+0] += vc[ci]*wv[ci][j4].x;
                acc[px][j4*4+1] += vc[ci]*wv[ci][j4].y;
                acc[px][j4*4+2] += vc[ci]*wv[ci][j4].z;
                acc[px][j4*4+3] += vc[ci]*wv[ci][j4].w;
              }
          }
        }
      }
    }
  }
  #pragma unroll
  for (int px=0;px<TX;px++){
    float* op = out + ((size_t)((n*Ho+y)*Wo + x0+px))*COUT + ob*TO;
    #pragma unroll
    for (int j4=0;j4<TO/4;j4++){
      float4 r;
      r.x = LRELU?lrelu_f(acc[px][j4*4+0]):acc[px][j4*4+0];
      r.y = LRELU?lrelu_f(acc[px][j4*4+1]):acc[px][j4*4+1];
      r.z = LRELU?lrelu_f(acc[px][j4*4+2]):acc[px][j4*4+2];
      r.w = LRELU?lrelu_f(acc[px][j4*4+3]):acc[px][j4*4+3];
      *(float4*)(op+j4*4) = r;
    }
  }
}

// ============ Fused enc4 (1x1 conv 64->32) + vector-quantize ============
template<int CIN,int D,int K>
__global__ __launch_bounds__(256) void enc4_vq_k(const float* __restrict__ in,
    const float* __restrict__ w, const float* __restrict__ bias,
    const float* __restrict__ cb, float* __restrict__ q, int npix){
  int i = blockIdx.x*256 + threadIdx.x;
  if (i >= npix) return;
  const float* ip = in + (size_t)i*CIN;
  float z[D];
  #pragma unroll
  for (int d=0; d<D; d++) z[d] = bias[d];
  for (int c=0; c<CIN; c+=4){
    float4 v = *(const float4*)(ip + c);
    #pragma unroll
    for (int d=0; d<D; d++){
      z[d] += v.x * w[(c+0)*D + d];
      z[d] += v.y * w[(c+1)*D + d];
      z[d] += v.z * w[(c+2)*D + d];
      z[d] += v.w * w[(c+3)*D + d];
    }
  }
  float z2 = 0.f;
  #pragma unroll
  for (int d=0; d<D; d++) z2 += z[d]*z[d];
  float best = 3.4e38f; int bi = 0;
  for (int k=0; k<K; k++){
    float e2 = 0.f, dot = 0.f;
    #pragma unroll
    for (int d=0; d<D; d++){
      float cv = cb[d*K + k];
      e2  += cv*cv;
      dot += z[d]*cv;
    }
    float dist = z2 + e2 - 2.f*dot;
    if (dist < best){ best = dist; bi = k; }   // strict < == first-min (jnp.argmin)
  }
  float* qp = q + (size_t)i*D;
  #pragma unroll
  for (int d=0; d<D; d++) qp[d] = cb[d*K + bi];
}

// ============ Decoder conv_transpose 3x3 s2 SAME (JAX, unflipped), parity body ============
template<int H,int W,int CIN,int COUT,int TO,int TX,int PY,int PX,bool LRELU>
__device__ __forceinline__ void deconv_body(const float* __restrict__ in,
    const float* __restrict__ w, const float* __restrict__ bias, float* __restrict__ out,
    int t){
  constexpr int Ho=2*H, Wo=2*W, OB=COUT/TO, XB=W/TX;
  int ob = t % OB; int p = t/OB;
  int xb = p % XB; p /= XB;
  int yy = p % H; int n = p/H;
  int x0 = xb*TX;

  float acc[TX][TO];
  #pragma unroll
  for (int j4=0;j4<TO/4;j4++){
    float4 bv = *(const float4*)(bias + ob*TO + j4*4);
    #pragma unroll
    for (int px=0;px<TX;px++){
      acc[px][j4*4+0]=bv.x; acc[px][j4*4+1]=bv.y;
      acc[px][j4*4+2]=bv.z; acc[px][j4*4+3]=bv.w;
    }
  }

  #pragma unroll
  for (int ky=0;ky<3;ky++){
    if ((PY+ky)&1) continue;              // compile-time parity filter
    const int dy = (PY+ky-2) >> 1;        // -1 or 0
    int iy = yy + dy;
    if (dy < 0 && iy < 0) continue;
    const float* row = in + ((size_t)n*H + iy)*(size_t)(W*CIN);
    #pragma unroll
    for (int kx=0;kx<3;kx++){
      if ((PX+kx)&1) continue;
      const int dx = (PX+kx-2) >> 1;      // -1 or 0
      const float* wp = w + ((ky*3+kx)*CIN)*COUT + ob*TO;
      const float* ipx[TX]; bool okx[TX];
      #pragma unroll
      for (int px=0;px<TX;px++){
        int ix = x0+px+dx;
        okx[px] = (ix >= 0);
        ipx[px] = row + (size_t)(okx[px] ? ix : 0)*CIN;
      }
      for (int c=0;c<CIN;c+=4){
        float4 wv[4][TO/4];
        #pragma unroll
        for (int ci=0;ci<4;ci++)
          #pragma unroll
          for (int j4=0;j4<TO/4;j4++)
            wv[ci][j4] = *(const float4*)(wp + (c+ci)*COUT + j4*4);
        #pragma unroll
        for (int px=0;px<TX;px++){
          float4 vv = *(const float4*)(ipx[px]+c);
          if (!okx[px]) vv = zero4();
          float vc[4] = {vv.x, vv.y, vv.z, vv.w};
          #pragma unroll
          for (int ci=0;ci<4;ci++)
            #pragma unroll
            for (int j4=0;j4<TO/4;j4++){
              acc[px][j4*4+0] += vc[ci]*wv[ci][j4].x;
              acc[px][j4*4+1] += vc[ci]*wv[ci][j4].y;
              acc[px][j4*4+2] += vc[ci]*wv[ci][j4].z;
              acc[px][j4*4+3] += vc[ci]*wv[ci][j4].w;
            }
        }
      }
    }
  }
  int yo = 2*yy + PY;
  #pragma unroll
  for (int px=0;px<TX;px++){
    int xo = 2*(x0+px) + PX;
    float* op = out + ((size_t)((n*Ho+yo)*Wo + xo))*COUT + ob*TO;
    #pragma unroll
    for (int j4=0;j4<TO/4;j4++){
      float4 r;
      r.x = LRELU?lrelu_f(acc[px][j4*4+0]):acc[px][j4*4+0];
      r.y = LRELU?lrelu_f(acc[px][j4*4+1]):acc[px][j4*4+1];
      r.z = LRELU?lrelu_f(acc[px][j4*4+2]):acc[px][j4*4+2];
      r.w = LRELU?lrelu_f(acc[px][j4*4+3]):acc[px][j4*4+3];
      *(float4*)(op+j4*4) = r;
    }
  }
}

// One kernel covers all 4 parities: blockIdx.y = parity (block-uniform switch).
template<int H,int W,int CIN,int COUT,int TO,int TX,bool LRELU>
__global__ __launch_bounds__(256) void deconv3x3_s2_k(const float* __restrict__ in,
    const float* __restrict__ w, const float* __restrict__ bias, float* __restrict__ out,
    int per_par){
  int t = blockIdx.x*256 + threadIdx.x;
  if (t >= per_par) return;
  switch (blockIdx.y){
    case 0:  deconv_body<H,W,CIN,COUT,TO,TX,0,0,LRELU>(in,w,bias,out,t); break;
    case 1:  deconv_body<H,W,CIN,COUT,TO,TX,0,1,LRELU>(in,w,bias,out,t); break;
    case 2:  deconv_body<H,W,CIN,COUT,TO,TX,1,0,LRELU>(in,w,bias,out,t); break;
    default: deconv_body<H,W,CIN,COUT,TO,TX,1,1,LRELU>(in,w,bias,out,t); break;
  }
}

// ============ dec4: s1 deconv == 3x3 pad-1 conv, Cout=1; TX outputs share input columns ====
template<int H,int W,int CIN,int TX>
__global__ __launch_bounds__(256) void conv3x3_s1_co1_k(const float* __restrict__ in,
    const float* __restrict__ w, const float* __restrict__ bias, float* __restrict__ out,
    int total){
  constexpr int XB = W/TX;
  int t = blockIdx.x*256 + threadIdx.x;
  if (t >= total) return;
  int xb = t % XB; int p = t/XB;
  int y  = p % H;  int n = p/H;
  int x0 = xb*TX;

  float acc[TX];
  #pragma unroll
  for (int px=0;px<TX;px++) acc[px] = bias[0];

  #pragma unroll
  for (int ky=0;ky<3;ky++){
    int iy = y + ky - 1;
    if (iy < 0 || iy >= H) continue;
    const float* row = in + ((size_t)n*H + iy)*(size_t)(W*CIN);
    const float* wk  = w + (ky*3)*CIN;
    for (int c=0;c<CIN;c+=4){
      float4 wv[3];
      #pragma unroll
      for (int kx=0;kx<3;kx++) wv[kx] = *(const float4*)(wk + kx*CIN + c);
      #pragma unroll
      for (int j=0;j<TX+2;j++){
        int ix = x0 + j - 1;
        bool ok = (ix >= 0 && ix < W);
        float4 v = *(const float4*)(row + (size_t)(ok ? ix : 0)*CIN + c);
        if (!ok) v = zero4();
        #pragma unroll
        for (int kx=0;kx<3;kx++){
          int px = j - kx;
          if (px >= 0 && px < TX){
            acc[px] += v.x*wv[kx].x + v.y*wv[kx].y + v.z*wv[kx].z + v.w*wv[kx].w;
          }
        }
      }
    }
  }
  float* op = out + (size_t)(n*H + y)*W + x0;
  if constexpr (TX == 4){
    float4 r; r.x=acc[0]; r.y=acc[1]; r.z=acc[2]; r.w=acc[3];
    *(float4*)op = r;
  } else {
    #pragma unroll
    for (int px=0;px<TX;px++) op[px] = acc[px];
  }
}

extern "C" void kernel_launch(void* const* d_in, const int* in_sizes, int n_in,
                              void* d_out, int out_size, void* d_ws, size_t ws_size,
                              hipStream_t stream) {
  const float* x   = (const float*)d_in[0];
  const float* e1w = (const float*)d_in[1];  const float* e1b = (const float*)d_in[2];
  const float* e2w = (const float*)d_in[3];  const float* e2b = (const float*)d_in[4];
  const float* e3w = (const float*)d_in[5];  const float* e3b = (const float*)d_in[6];
  const float* e4w = (const float*)d_in[7];  const float* e4b = (const float*)d_in[8];
  const float* cb  = (const float*)d_in[9];
  const float* d1w = (const float*)d_in[10]; const float* d1b = (const float*)d_in[11];
  const float* d2w = (const float*)d_in[12]; const float* d2b = (const float*)d_in[13];
  const float* d3w = (const float*)d_in[14]; const float* d3b = (const float*)d_in[15];
  const float* d4w = (const float*)d_in[16]; const float* d4b = (const float*)d_in[17];
  float* out = (float*)d_out;

  // Per-image ping-pong: A = max(h1,h3,d1,d3) = 8 MiB/img; B = max(h2,q,d2) = 4 MiB/img.
  const size_t MiB = 1ull << 20;
  int Bc = 32;
  while (Bc > 1 && (size_t)Bc * 12 * MiB > ws_size) Bc >>= 1;

  char* wsb = (char*)d_ws;
  float* A  = (float*)wsb;                              // Bc * 8 MiB
  float* Bf = (float*)(wsb + (size_t)Bc * 8 * MiB);     // Bc * 4 MiB

  for (int n0 = 0; n0 < 32; n0 += Bc) {
    const float* xc = x   + (size_t)n0 * 256*256*3;
    float*      oc  = out + (size_t)n0 * 256*256;

    // enc1: [Bc,256,256,3] -> [Bc,128,128,32]; TO=8(OB=4), TX=2(XB=64)
    int t1 = Bc*128*64*4;
    conv3x3_s2_k<256,256,3,32,8,2,true><<<t1/256,256,0,stream>>>(xc, e1w, e1b, A, t1);
    // enc2: -> [Bc,64,64,64]; TO=8(OB=8), TX=2(XB=32)
    int t2 = Bc*64*32*8;
    conv3x3_s2_k<128,128,32,64,8,2,true><<<t2/256,256,0,stream>>>(A, e2w, e2b, Bf, t2);
    // enc3: -> [Bc,32,32,64]; TX=2(XB=16)
    int t3 = Bc*32*16*8;
    conv3x3_s2_k<64,64,64,64,8,2,true><<<t3/256,256,0,stream>>>(Bf, e3w, e3b, A, t3);
    // enc4 (1x1, 64->32) + VQ: -> q [Bc,32,32,32]
    int npix = Bc*32*32;
    enc4_vq_k<64,32,64><<<npix/256,256,0,stream>>>(A, e4w, e4b, cb, Bf, npix);
    // dec1: [Bc,32,32,32] -> [Bc,64,64,64]; TO=8, TX=2; per-parity = Bc*32*16*8
    {
      int pp = Bc*32*16*8;
      dim3 g(pp/256, 4);
      deconv3x3_s2_k<32,32,32,64,8,2,true><<<g,256,0,stream>>>(Bf, d1w, d1b, A, pp);
    }
    // dec2: -> [Bc,128,128,64]; TO=8, TX=4; per-parity = Bc*64*16*8
    {
      int pp = Bc*64*16*8;
      dim3 g(pp/256, 4);
      deconv3x3_s2_k<64,64,64,64,8,4,true><<<g,256,0,stream>>>(A, d2w, d2b, Bf, pp);
    }
    // dec3: -> [Bc,256,256,32]; TO=8(OB=4), TX=4; per-parity = Bc*128*32*4
    {
      int pp = Bc*128*32*4;
      dim3 g(pp/256, 4);
      deconv3x3_s2_k<128,128,64,32,8,4,true><<<g,256,0,stream>>>(Bf, d3w, d3b, A, pp);
    }
    // dec4: -> [Bc,256,256,1]; TX=4
    int t8 = Bc*256*64;
    conv3x3_s1_co1_k<256,256,32,4><<<t8/256,256,0,stream>>>(A, d4w, d4b, oc, t8);
  }
}